// Round 3
// baseline (1480.507 us; speedup 1.0000x reference)
//
#include <hip/hip_runtime.h>
#include <cstddef>

#define HD 8
#define C2 16
#define HH 28
#define WW 28
#define BB 16
#define SP (HH*WW)           // 784
#define FEAT (HD*SP)         // 6272
#define FEAT2 (C2*SP)        // 12544

#define TILE_ROWS 2
#define NT (HH/TILE_ROWS)    // 14
#define BLK_PER_NODE (BB*NT) // 224
#define NBLK (3*BLK_PER_NODE) // 672

__device__ __forceinline__ float sigf(float x) { return 1.0f / (1.0f + expf(-x)); }

struct Smem {
    float gw[C2*C2*9];                 // 2304 f
    float cw[HD*C2*9];                 // 1152 f
    float gb[C2];
    float cb[HD];
    float comb[C2][TILE_ROWS+4][32];   // 3072 f
    float cin[C2][TILE_ROWS+2][32];    // 2048 f
    int   flags[2];
};

// Monotonic grid barrier: every block arrives exactly once per call site;
// target = (call index)*NBLK. cnt is zeroed by init_kernel each launch, so
// no reset inside the kernel -> no reset/arrival race. __threadfence()
// (agent-scope fence: L2 writeback + invalidate) makes cross-XCD data visible.
__device__ __forceinline__ void gbar(unsigned* cnt, unsigned target) {
    __syncthreads();
    if (threadIdx.x == 0) {
        __threadfence();
        atomicAdd(cnt, 1u);
        while (atomicAdd(cnt, 0u) < target)
            __builtin_amdgcn_s_sleep(8);
        __threadfence();
    }
    __syncthreads();
}

// One ConvGRU cell for tile (bi, r0) using this block's LDS-resident weights.
__device__ void gru_cell_dev(Smem& sm, int tid, int bi, int r0,
                             const float* x, const float* h,
                             const float* td, const float* td_bias,
                             bool use_bias, float xscale,
                             float* hout, int* out_flag) {
    // Phase A1: combined = concat([xscale*x, h]) * sigmoid(td), zero-padded tile
    for (int i = tid; i < C2*(TILE_ROWS+4)*32; i += 256) {
        int cidx = i & 31;
        int ridx = (i >> 5) % (TILE_ROWS+4);
        int c    = i / ((TILE_ROWS+4)*32);
        int row = r0 - 2 + ridx;
        int col = cidx - 2;
        float v = 0.0f;
        if (row >= 0 && row < HH && col >= 0 && col < WW) {
            float base = 0.0f;
            if (c < HD) { if (x) base = xscale * x[((size_t)bi*HD + c)*SP + row*WW + col]; }
            else        { if (h) base = h[((size_t)bi*HD + (c-HD))*SP + row*WW + col]; }
            if (base != 0.0f) {
                float tdv = use_bias ? td_bias[c*SP + row*WW + col]
                                     : td[((size_t)bi*C2 + c)*SP + row*WW + col];
                v = base * sigf(tdv);
            }
        }
        sm.comb[c][ridx][cidx] = v;
    }
    // Phase A2: cand-input channels 0..7 = xscale * x (unmodulated)
    for (int i = tid; i < HD*(TILE_ROWS+2)*32; i += 256) {
        int cidx = i & 31;
        int ridx = (i >> 5) % (TILE_ROWS+2);
        int c    = i / ((TILE_ROWS+2)*32);
        int row = r0 - 1 + ridx;
        int col = cidx - 1;
        float v = 0.0f;
        if (x && row >= 0 && row < HH && col >= 0 && col < WW)
            v = xscale * x[((size_t)bi*HD + c)*SP + row*WW + col];
        sm.cin[c][ridx][cidx] = v;
    }
    __syncthreads();

    // Phase B: r gates at rows r0-1..r0+2 (4) x cols -1..28 (30) x 8ch (2 halves)
    if (tid < (TILE_ROWS+2)*30*2) {
        int half  = tid & 1;
        int pos   = tid >> 1;
        int ridx2 = pos / 30;
        int cp    = pos % 30;
        float acc0 = sm.gb[half*4+0], acc1 = sm.gb[half*4+1],
              acc2 = sm.gb[half*4+2], acc3 = sm.gb[half*4+3];
        for (int ic = 0; ic < C2; ++ic) {
            float cv[3][3];
            #pragma unroll
            for (int dy = 0; dy < 3; ++dy)
                #pragma unroll
                for (int dx = 0; dx < 3; ++dx)
                    cv[dy][dx] = sm.comb[ic][ridx2+dy][cp+dx];
            const float* wp = &sm.gw[(half*4*C2 + ic)*9];
            #pragma unroll
            for (int dy = 0; dy < 3; ++dy)
                #pragma unroll
                for (int dx = 0; dx < 3; ++dx) {
                    float cvv = cv[dy][dx];
                    acc0 += cvv * wp[0*C2*9 + dy*3+dx];
                    acc1 += cvv * wp[1*C2*9 + dy*3+dx];
                    acc2 += cvv * wp[2*C2*9 + dy*3+dx];
                    acc3 += cvv * wp[3*C2*9 + dy*3+dx];
                }
        }
        int row = r0 - 1 + ridx2;
        int col = cp - 1;
        bool inb = (row >= 0 && row < HH && col >= 0 && col < WW);
        float av[4] = {acc0, acc1, acc2, acc3};
        #pragma unroll
        for (int o = 0; o < 4; ++o) {
            int ch = half*4 + o;
            float hv = 0.0f;
            if (h && inb) hv = h[((size_t)bi*HD + ch)*SP + row*WW + col];
            sm.cin[HD + ch][ridx2][cp] = sigf(av[o]) * hv;
        }
    }
    __syncthreads();

    // Phase C: u gate + cand conv + blend
    bool nz = false;
    for (int item = tid; item < TILE_ROWS*WW*HD; item += 256) {
        int c   = item / (TILE_ROWS*WW);
        int rem = item % (TILE_ROWS*WW);
        int rr  = rem / WW;
        int col = rem % WW;
        float uacc = sm.gb[HD + c];
        float cacc = sm.cb[c];
        for (int ic = 0; ic < C2; ++ic) {
            const float* uwp = &sm.gw[((HD + c)*C2 + ic)*9];
            const float* cwp = &sm.cw[(c*C2 + ic)*9];
            #pragma unroll
            for (int dy = 0; dy < 3; ++dy)
                #pragma unroll
                for (int dx = 0; dx < 3; ++dx) {
                    uacc += sm.comb[ic][rr+1+dy][col+1+dx] * uwp[dy*3+dx];
                    cacc += sm.cin[ic][rr+dy][col+dx]      * cwp[dy*3+dx];
                }
        }
        float u    = sigf(uacc);
        float cand = tanhf(cacc);
        int row = r0 + rr;
        size_t oidx = ((size_t)bi*HD + c)*SP + row*WW + col;
        float hv = h ? h[oidx] : 0.0f;
        float outv = (1.0f - u) * hv + u * cand;
        hout[oidx] = outv;
        nz |= (outv != 0.0f);
    }
    if (out_flag) {
        unsigned long long m = __ballot(nz);
        if ((tid & 63) == 0 && m) atomicOr(out_flag, 1);
    }
    __syncthreads();   // LDS reuse safety before any later phase
}

__global__ void init_kernel(unsigned* cnt, int* flags) {
    if (threadIdx.x == 0) {
        atomicExch(cnt, 0u);
        atomicExch(&flags[0], 0);
        atomicExch(&flags[1], 0);
    }
}

__global__ __launch_bounds__(256, 3)
void mega_kernel(const float* __restrict__ input_tensor, const float* __restrict__ topdown,
                 const float* __restrict__ icw, const float* __restrict__ icb,
                 const float* __restrict__ gates_w, const float* __restrict__ gates_b,
                 const float* __restrict__ can_w, const float* __restrict__ can_b,
                 const float* __restrict__ td_w0, const float* __restrict__ td_b0,
                 const float* __restrict__ td_w1, const float* __restrict__ td_b1,
                 const float* __restrict__ fc1_w, const float* __restrict__ fc1_b,
                 const float* __restrict__ fc2_w, const float* __restrict__ fc2_b,
                 float* __restrict__ out,
                 float* __restrict__ x0,
                 float* __restrict__ h00, float* __restrict__ h01, float* __restrict__ h02,
                 float* __restrict__ h10, float* __restrict__ h11, float* __restrict__ h12,
                 float* __restrict__ td0, float* __restrict__ td1,
                 float* __restrict__ p1,
                 int* flags, unsigned* cnt)
{
    const int tid   = threadIdx.x;
    const int blk   = blockIdx.x;
    const int node  = blk / BLK_PER_NODE;
    const int local = blk % BLK_PER_NODE;
    const int bi    = local / NT;
    const int r0    = (local % NT) * TILE_ROWS;

    __shared__ Smem sm;

    // Stage this node's weights once; reused by both sweeps.
    {
        const float* gw = gates_w + node*C2*C2*9;
        const float* cw = can_w   + node*HD*C2*9;
        for (int i = tid; i < C2*C2*9; i += 256) sm.gw[i] = gw[i];
        for (int i = tid; i < HD*C2*9; i += 256) sm.cw[i] = cw[i];
        if (tid < C2) sm.gb[tid] = gates_b[node*C2 + tid];
        if (tid < HD) sm.cb[tid] = can_b[node*HD + tid];
    }

    // Phase 0: input conv (all blocks share the work)
    {
        int idx = blk*256 + tid;
        if (idx < BB*HD*SP) {
            int col = idx % WW;
            int row = (idx / SP == idx / SP ? (idx / WW) % HH : 0);
            row = (idx / WW) % HH;
            int oc  = (idx / SP) % HD;
            int b2  = idx / (HD*SP);
            float acc = icb[oc];
            for (int c = 0; c < 3; ++c)
                #pragma unroll
                for (int dy = 0; dy < 3; ++dy) {
                    int rr = row + dy - 1;
                    if (rr < 0 || rr >= HH) continue;
                    #pragma unroll
                    for (int dx = 0; dx < 3; ++dx) {
                        int cc = col + dx - 1;
                        if (cc < 0 || cc >= WW) continue;
                        acc += input_tensor[((size_t)b2*3 + c)*SP + rr*WW + cc]
                             * icw[((oc*3 + c)*3 + dy)*3 + dx];
                    }
                }
            x0[idx] = acc;
        }
    }
    gbar(cnt, 1u*NBLK);

    // Phase 1: sweep 0 (3 nodes in parallel; prev state structurally zero)
    {
        const float* x  = (node == 0) ? x0 : nullptr;
        const float* td = (node == 2) ? topdown : nullptr;
        const float* tb = (node == 0) ? td_b0 : (node == 1) ? td_b1 : nullptr;
        float xs        = (node == 0) ? 1.0f : (node == 1) ? 0.8f : 0.7f;
        float* ho       = (node == 0) ? h00 : (node == 1) ? h01 : h02;
        int* of         = (node == 1) ? flags+0 : (node == 2) ? flags+1 : nullptr;
        gru_cell_dev(sm, tid, bi, r0, x, nullptr, td, tb, node != 2, xs, ho, of);
    }
    gbar(cnt, 2u*NBLK);

    if (tid == 0) {
        sm.flags[0] = atomicAdd(&flags[0], 0);
        sm.flags[1] = atomicAdd(&flags[1], 0);
    }
    __syncthreads();

    // Phase 2: flag-gated td projections (dead when sweep-0 states are zero)
    if (sm.flags[0] | sm.flags[1]) {
        int gtid = blk*256 + tid;
        if (gtid < 2*FEAT2) {
            int nn = gtid / FEAT2;
            int j  = gtid % FEAT2;
            if (sm.flags[nn]) {
                const float* hin  = nn ? h02 : h01;
                const float* w    = nn ? td_w1 : td_w0;
                const float* bias = nn ? td_b1 : td_b0;
                float* o          = nn ? td1 : td0;
                float scale       = nn ? 0.5f : 0.6f;
                float acc[BB];
                #pragma unroll
                for (int q = 0; q < BB; ++q) acc[q] = 0.0f;
                const float* wr = w + (size_t)j * FEAT;
                for (int k = 0; k < FEAT; ++k) {
                    float wv = wr[k];
                    #pragma unroll
                    for (int q = 0; q < BB; ++q)
                        acc[q] += (scale * hin[(size_t)q*FEAT + k]) * wv;
                }
                #pragma unroll
                for (int q = 0; q < BB; ++q) o[(size_t)q*FEAT2 + j] = acc[q] + bias[j];
            }
        }
    }
    gbar(cnt, 3u*NBLK);

    // Phase 3: sweep-1 node 0
    if (node == 0)
        gru_cell_dev(sm, tid, bi, r0, x0, h00, td0, td_b0, sm.flags[0] == 0, 1.0f, h10, nullptr);
    gbar(cnt, 4u*NBLK);

    // Phase 4: sweep-1 node 1 (sees h10)
    if (node == 1)
        gru_cell_dev(sm, tid, bi, r0, h10, h01, td1, td_b1, sm.flags[1] == 0, 0.8f, h11, nullptr);
    gbar(cnt, 5u*NBLK);

    // Phase 5: sweep-1 node 2 (sees h11)
    if (node == 2)
        gru_cell_dev(sm, tid, bi, r0, h11, h02, topdown, nullptr, false, 0.7f, h12, nullptr);
    gbar(cnt, 6u*NBLK);

    // Phase 6: fc1 on blocks 0..99 (one output column each, 4 waves x 4 batches)
    if (blk < 100) {
        int j    = blk;
        int wave = tid >> 6;
        int lane = tid & 63;
        float acc[4] = {0.f, 0.f, 0.f, 0.f};
        const float* wr = fc1_w + (size_t)j * FEAT;
        for (int k = lane; k < FEAT; k += 64) {
            float wv = wr[k];
            #pragma unroll
            for (int q = 0; q < 4; ++q) {
                float v = h12[(size_t)(wave*4+q)*FEAT + k];
                acc[q] += fmaxf(v, 0.0f) * wv;
            }
        }
        #pragma unroll
        for (int off = 32; off > 0; off >>= 1)
            #pragma unroll
            for (int q = 0; q < 4; ++q)
                acc[q] += __shfl_down(acc[q], off);
        if (lane == 0) {
            #pragma unroll
            for (int q = 0; q < 4; ++q)
                p1[(size_t)(wave*4+q)*100 + j] = acc[q] + fc1_b[j];
        }
    }
    gbar(cnt, 7u*NBLK);

    // Phase 7: fc2 on block 0
    if (blk == 0 && tid < BB*10) {
        int b2 = tid / 10, j = tid % 10;
        float acc = fc2_b[j];
        for (int k = 0; k < 100; ++k)
            acc += fmaxf(p1[b2*100 + k], 0.0f) * fc2_w[j*100 + k];
        out[b2*10 + j] = acc;
    }
}

extern "C" void kernel_launch(void* const* d_in, const int* in_sizes, int n_in,
                              void* d_out, int out_size, void* d_ws, size_t ws_size,
                              hipStream_t stream) {
    const float* input_tensor = (const float*)d_in[0];
    const float* topdown      = (const float*)d_in[1];
    const float* icw  = (const float*)d_in[2];
    const float* icb  = (const float*)d_in[3];
    const float* gates_w = (const float*)d_in[4];
    const float* gates_b = (const float*)d_in[5];
    const float* can_w   = (const float*)d_in[6];
    const float* can_b   = (const float*)d_in[7];
    const float* td_w0 = (const float*)d_in[8];
    const float* td_b0 = (const float*)d_in[9];
    const float* td_w1 = (const float*)d_in[10];
    const float* td_b1 = (const float*)d_in[11];
    const float* fc1_w = (const float*)d_in[12];
    const float* fc1_b = (const float*)d_in[13];
    const float* fc2_w = (const float*)d_in[14];
    const float* fc2_b = (const float*)d_in[15];
    float* out = (float*)d_out;

    float* ws  = (float*)d_ws;
    float* x0  = ws;
    float* h00 = x0  + BB*HD*SP;
    float* h01 = h00 + BB*HD*SP;
    float* h02 = h01 + BB*HD*SP;
    float* h10 = h02 + BB*HD*SP;
    float* h11 = h10 + BB*HD*SP;
    float* h12 = h11 + BB*HD*SP;
    float* td0 = h12 + BB*HD*SP;
    float* td1 = td0 + BB*C2*SP;
    float* p1  = td1 + BB*C2*SP;
    int* flags = (int*)(p1 + BB*100);
    unsigned* cnt = (unsigned*)(flags + 2);

    init_kernel<<<1, 64, 0, stream>>>(cnt, flags);
    mega_kernel<<<NBLK, 256, 0, stream>>>(
        input_tensor, topdown, icw, icb, gates_w, gates_b, can_w, can_b,
        td_w0, td_b0, td_w1, td_b1, fc1_w, fc1_b, fc2_w, fc2_b, out,
        x0, h00, h01, h02, h10, h11, h12, td0, td1, p1, flags, cnt);
}

// Round 4
// 473.351 us; speedup vs baseline: 3.1277x; 3.1277x over previous
//
#include <hip/hip_runtime.h>
#include <cstddef>

#define HD 8
#define C2 16
#define HH 28
#define WW 28
#define BB 16
#define SP (HH*WW)           // 784
#define FEAT (HD*SP)         // 6272
#define FEAT2 (C2*SP)        // 12544

#define TILE_ROWS 2
#define NT (HH/TILE_ROWS)    // 14
#define NBLK (BB*NT)         // 224 blocks, one per (batch, row-tile)

__device__ __forceinline__ float sigf(float x) { return 1.0f / (1.0f + expf(-x)); }

struct Smem {
    float gw[C2*C2*9];                 // current node's gate weights
    float cw[HD*C2*9];                 // current node's cand weights
    float gb[C2];
    float cb[HD];
    float icw[HD*3*9];
    float icb[HD];
    float x0t[HD][TILE_ROWS+4][32];    // input-conv tile, rows r0-2..r0+3, cols -2..29
    float comb[C2][TILE_ROWS+4][32];
    union {
        float cin[C2][TILE_ROWS+2][32];
        float s_in[3][TILE_ROWS+6][36]; // raw input tile rows r0-3..r0+4, cols -3..32
    } u;
    int flags[2];
};

// Grid barrier, zero-RMW: arrival = release-store of epoch into a private
// 64B slot; block 0 aggregates (224 parallel pollers, one line each) and
// publishes `done`; everyone else polls the single `done` line.
__device__ __forceinline__ void gbar(unsigned* slots, unsigned* done, int blk, unsigned ep) {
    __syncthreads();
    __threadfence();   // make this block's global writes visible device-wide
    if (threadIdx.x == 0)
        __hip_atomic_store(&slots[(size_t)blk * 16], ep,
                           __ATOMIC_RELEASE, __HIP_MEMORY_SCOPE_AGENT);
    if (blk == 0) {
        int t = threadIdx.x;
        if (t < NBLK) {
            while (__hip_atomic_load(&slots[(size_t)t * 16],
                                     __ATOMIC_RELAXED, __HIP_MEMORY_SCOPE_AGENT) < ep)
                __builtin_amdgcn_s_sleep(2);
        }
        __syncthreads();
        __threadfence();
        if (threadIdx.x == 0)
            __hip_atomic_store(done, ep, __ATOMIC_RELEASE, __HIP_MEMORY_SCOPE_AGENT);
    } else {
        if (threadIdx.x == 0) {
            while (__hip_atomic_load(done, __ATOMIC_RELAXED,
                                     __HIP_MEMORY_SCOPE_AGENT) < ep)
                __builtin_amdgcn_s_sleep(2);
        }
    }
    __threadfence();   // invalidate stale caches before reading others' data
    __syncthreads();
}

// One ConvGRU cell for tile (bi, r0). Weights must already be in sm.gw/cw/gb/cb.
// x source: if x_lds, read sm.x0t (xscale applied); else global x (or zeros if null).
__device__ void gru_cell_dev(Smem& sm, int tid, int bi, int r0,
                             const float* x, bool x_lds, float xscale,
                             const float* h,
                             const float* td, const float* td_bias, bool use_bias,
                             float* hout, int* out_flag, int* flags) {
    // Phase A1: combined = concat([xscale*x, h]) * sigmoid(td), zero-padded tile
    for (int i = tid; i < C2*(TILE_ROWS+4)*32; i += 256) {
        int cidx = i & 31;
        int ridx = (i >> 5) % (TILE_ROWS+4);
        int c    = i / ((TILE_ROWS+4)*32);
        int row = r0 - 2 + ridx;
        int col = cidx - 2;
        float v = 0.0f;
        if (row >= 0 && row < HH && col >= 0 && col < WW) {
            float base = 0.0f;
            if (c < HD) {
                if (x_lds)      base = xscale * sm.x0t[c][ridx][cidx];
                else if (x)     base = xscale * x[((size_t)bi*HD + c)*SP + row*WW + col];
            } else {
                if (h)          base = h[((size_t)bi*HD + (c-HD))*SP + row*WW + col];
            }
            if (base != 0.0f) {
                float tdv = use_bias ? td_bias[c*SP + row*WW + col]
                                     : td[((size_t)bi*C2 + c)*SP + row*WW + col];
                v = base * sigf(tdv);
            }
        }
        sm.comb[c][ridx][cidx] = v;
    }
    // Phase A2: cand-input channels 0..7 = xscale * x (unmodulated)
    for (int i = tid; i < HD*(TILE_ROWS+2)*32; i += 256) {
        int cidx = i & 31;
        int ridx = (i >> 5) % (TILE_ROWS+2);
        int c    = i / ((TILE_ROWS+2)*32);
        int row = r0 - 1 + ridx;
        int col = cidx - 1;
        float v = 0.0f;
        if (row >= 0 && row < HH && col >= 0 && col < WW) {
            if (x_lds)      v = xscale * sm.x0t[c][ridx+1][cidx+1];
            else if (x)     v = xscale * x[((size_t)bi*HD + c)*SP + row*WW + col];
        }
        sm.u.cin[c][ridx][cidx] = v;
    }
    __syncthreads();

    // Phase B: r gates at rows r0-1..r0+2 (4) x cols -1..28 (30) x 8ch (2 halves)
    if (tid < (TILE_ROWS+2)*30*2) {
        int half  = tid & 1;
        int pos   = tid >> 1;
        int ridx2 = pos / 30;
        int cp    = pos % 30;
        float acc0 = sm.gb[half*4+0], acc1 = sm.gb[half*4+1],
              acc2 = sm.gb[half*4+2], acc3 = sm.gb[half*4+3];
        for (int ic = 0; ic < C2; ++ic) {
            float cv[3][3];
            #pragma unroll
            for (int dy = 0; dy < 3; ++dy)
                #pragma unroll
                for (int dx = 0; dx < 3; ++dx)
                    cv[dy][dx] = sm.comb[ic][ridx2+dy][cp+dx];
            const float* wp = &sm.gw[(half*4*C2 + ic)*9];
            #pragma unroll
            for (int dy = 0; dy < 3; ++dy)
                #pragma unroll
                for (int dx = 0; dx < 3; ++dx) {
                    float cvv = cv[dy][dx];
                    acc0 += cvv * wp[0*C2*9 + dy*3+dx];
                    acc1 += cvv * wp[1*C2*9 + dy*3+dx];
                    acc2 += cvv * wp[2*C2*9 + dy*3+dx];
                    acc3 += cvv * wp[3*C2*9 + dy*3+dx];
                }
        }
        int row = r0 - 1 + ridx2;
        int col = cp - 1;
        bool inb = (row >= 0 && row < HH && col >= 0 && col < WW);
        float av[4] = {acc0, acc1, acc2, acc3};
        #pragma unroll
        for (int o = 0; o < 4; ++o) {
            int ch = half*4 + o;
            float hv = 0.0f;
            if (h && inb) hv = h[((size_t)bi*HD + ch)*SP + row*WW + col];
            sm.u.cin[HD + ch][ridx2][cp] = sigf(av[o]) * hv;
        }
    }
    __syncthreads();

    // Phase C: u gate + cand conv + blend
    bool nz = false;
    for (int item = tid; item < TILE_ROWS*WW*HD; item += 256) {
        int c   = item / (TILE_ROWS*WW);
        int rem = item % (TILE_ROWS*WW);
        int rr  = rem / WW;
        int col = rem % WW;
        float uacc = sm.gb[HD + c];
        float cacc = sm.cb[c];
        for (int ic = 0; ic < C2; ++ic) {
            const float* uwp = &sm.gw[((HD + c)*C2 + ic)*9];
            const float* cwp = &sm.cw[(c*C2 + ic)*9];
            #pragma unroll
            for (int dy = 0; dy < 3; ++dy)
                #pragma unroll
                for (int dx = 0; dx < 3; ++dx) {
                    uacc += sm.comb[ic][rr+1+dy][col+1+dx] * uwp[dy*3+dx];
                    cacc += sm.u.cin[ic][rr+dy][col+dx]    * cwp[dy*3+dx];
                }
        }
        float u    = sigf(uacc);
        float cand = tanhf(cacc);
        int row = r0 + rr;
        size_t oidx = ((size_t)bi*HD + c)*SP + row*WW + col;
        float hv = h ? h[oidx] : 0.0f;
        float outv = (1.0f - u) * hv + u * cand;
        hout[oidx] = outv;
        nz |= (outv != 0.0f);
    }
    if (out_flag) {
        unsigned long long m = __ballot(nz);
        if ((tid & 63) == 0 && m) atomicOr(out_flag, 1);
    }
    __syncthreads();   // LDS safe for reuse
}

__global__ void init_kernel(unsigned* slots, unsigned* done, int* flags) {
    int t = threadIdx.x;
    for (int i = t; i < NBLK*16; i += 256) slots[i] = 0u;
    if (t == 0) { *done = 0u; flags[0] = 0; flags[1] = 0; }
}

__global__ __launch_bounds__(256)
void mega_kernel(const float* __restrict__ input_tensor, const float* __restrict__ topdown,
                 const float* __restrict__ icw, const float* __restrict__ icb,
                 const float* __restrict__ gates_w, const float* __restrict__ gates_b,
                 const float* __restrict__ can_w, const float* __restrict__ can_b,
                 const float* __restrict__ td_w0, const float* __restrict__ td_b0,
                 const float* __restrict__ td_w1, const float* __restrict__ td_b1,
                 const float* __restrict__ fc1_w, const float* __restrict__ fc1_b,
                 const float* __restrict__ fc2_w, const float* __restrict__ fc2_b,
                 float* __restrict__ out,
                 float* __restrict__ h00, float* __restrict__ h01, float* __restrict__ h02,
                 float* __restrict__ h10, float* __restrict__ h11, float* __restrict__ h12,
                 float* __restrict__ td0, float* __restrict__ td1,
                 float* __restrict__ p1,
                 int* flags, unsigned* slots, unsigned* done)
{
    const int tid = threadIdx.x;
    const int blk = blockIdx.x;
    const int bi  = blk / NT;
    const int r0  = (blk % NT) * TILE_ROWS;

    __shared__ Smem sm;
    unsigned ep = 0;

    // ---- Phase S0 (no prior barrier): node-0 weights + local input-conv tile ----
    for (int i = tid; i < C2*C2*9; i += 256) sm.gw[i] = gates_w[i];
    for (int i = tid; i < HD*C2*9; i += 256) sm.cw[i] = can_w[i];
    if (tid < C2) sm.gb[tid] = gates_b[tid];
    if (tid < HD) sm.cb[tid] = can_b[tid];
    for (int i = tid; i < HD*3*9; i += 256) sm.icw[i] = icw[i];
    if (tid < HD) sm.icb[tid] = icb[tid];

    // raw input tile rows r0-3..r0+4, cols -3..32 (zero-padded)
    for (int i = tid; i < 3*(TILE_ROWS+6)*36; i += 256) {
        int ci = i % 36;
        int ri = (i / 36) % (TILE_ROWS+6);
        int c  = i / ((TILE_ROWS+6)*36);
        int row = r0 - 3 + ri;
        int col = ci - 3;
        float v = 0.0f;
        if (row >= 0 && row < HH && col >= 0 && col < WW)
            v = input_tensor[((size_t)bi*3 + c)*SP + row*WW + col];
        sm.u.s_in[c][ri][ci] = v;
    }
    __syncthreads();

    // x0 tile with halo: rows r0-2..r0+3, cols -2..29
    for (int i = tid; i < HD*(TILE_ROWS+4)*32; i += 256) {
        int ci = i & 31;
        int ri = (i >> 5) % (TILE_ROWS+4);
        int oc = i / ((TILE_ROWS+4)*32);
        int row = r0 - 2 + ri;
        int col = ci - 2;
        float v = 0.0f;
        if (row >= 0 && row < HH && col >= 0 && col < WW) {
            float acc = sm.icb[oc];
            for (int ic = 0; ic < 3; ++ic)
                #pragma unroll
                for (int dy = 0; dy < 3; ++dy)
                    #pragma unroll
                    for (int dx = 0; dx < 3; ++dx)
                        acc += sm.u.s_in[ic][ri+dy][ci+dx]
                             * sm.icw[((oc*3 + ic)*3 + dy)*3 + dx];
            v = acc;
        }
        sm.x0t[oc][ri][ci] = v;
    }
    __syncthreads();

    // Sweep-0 node 0: x = x0 tile, h = 0, td = bias-reshape
    gru_cell_dev(sm, tid, bi, r0, nullptr, true, 1.0f, nullptr,
                 nullptr, td_b0, true, h00, nullptr, flags);

    // Sweep-0 nodes 1,2: x=0, h=0 => comb==0 regardless of td, so the cell
    // reduces exactly to per-channel constants sig(gb_u[c]) * tanh(cb[c]).
    {
        bool nz1 = false, nz2 = false;
        for (int item = tid; item < TILE_ROWS*WW*HD; item += 256) {
            int c   = item / (TILE_ROWS*WW);
            int rem = item % (TILE_ROWS*WW);
            int rr  = rem / WW;
            int col = rem % WW;
            float v1 = sigf(gates_b[C2 + HD + c])   * tanhf(can_b[HD + c]);
            float v2 = sigf(gates_b[2*C2 + HD + c]) * tanhf(can_b[2*HD + c]);
            size_t oidx = ((size_t)bi*HD + c)*SP + (r0 + rr)*WW + col;
            h01[oidx] = v1;
            h02[oidx] = v2;
            nz1 |= (v1 != 0.0f);
            nz2 |= (v2 != 0.0f);
        }
        unsigned long long m1 = __ballot(nz1), m2 = __ballot(nz2);
        if ((tid & 63) == 0) {
            if (m1) atomicOr(&flags[0], 1);
            if (m2) atomicOr(&flags[1], 1);
        }
    }
    gbar(slots, done, blk, ++ep);

    // flags are now globally consistent -> uniform branch across the grid
    if (tid == 0) {
        sm.flags[0] = __hip_atomic_load(&flags[0], __ATOMIC_RELAXED, __HIP_MEMORY_SCOPE_AGENT);
        sm.flags[1] = __hip_atomic_load(&flags[1], __ATOMIC_RELAXED, __HIP_MEMORY_SCOPE_AGENT);
    }
    __syncthreads();
    const int f0 = sm.flags[0], f1 = sm.flags[1];

    // ---- td projections (dead on this data; kept for generality) ----
    if (f0 | f1) {
        int gtid = blk*256 + tid;
        if (gtid < 2*FEAT2) {
            int nn = gtid / FEAT2;
            int j  = gtid % FEAT2;
            if (nn ? f1 : f0) {
                const float* hin  = nn ? h02 : h01;
                const float* w    = nn ? td_w1 : td_w0;
                const float* bias = nn ? td_b1 : td_b0;
                float* o          = nn ? td1 : td0;
                float scale       = nn ? 0.5f : 0.6f;
                float acc[BB];
                #pragma unroll
                for (int q = 0; q < BB; ++q) acc[q] = 0.0f;
                const float* wr = w + (size_t)j * FEAT;
                for (int k = 0; k < FEAT; ++k) {
                    float wv = wr[k];
                    #pragma unroll
                    for (int q = 0; q < BB; ++q)
                        acc[q] += (scale * hin[(size_t)q*FEAT + k]) * wv;
                }
                #pragma unroll
                for (int q = 0; q < BB; ++q) o[(size_t)q*FEAT2 + j] = acc[q] + bias[j];
            }
        }
        gbar(slots, done, blk, ++ep);
    }

    // ---- Sweep 1, node 0 (node-0 weights still resident in LDS) ----
    gru_cell_dev(sm, tid, bi, r0, nullptr, true, 1.0f, h00,
                 td0, td_b0, f0 == 0, h10, nullptr, flags);
    gbar(slots, done, blk, ++ep);

    // ---- Sweep 1, node 1 ----
    for (int i = tid; i < C2*C2*9; i += 256) sm.gw[i] = gates_w[C2*C2*9 + i];
    for (int i = tid; i < HD*C2*9; i += 256) sm.cw[i] = can_w[HD*C2*9 + i];
    if (tid < C2) sm.gb[tid] = gates_b[C2 + tid];
    if (tid < HD) sm.cb[tid] = can_b[HD + tid];
    gru_cell_dev(sm, tid, bi, r0, h10, false, 0.8f, h01,
                 td1, td_b1, f1 == 0, h11, nullptr, flags);
    gbar(slots, done, blk, ++ep);

    // ---- Sweep 1, node 2 ----
    for (int i = tid; i < C2*C2*9; i += 256) sm.gw[i] = gates_w[2*C2*C2*9 + i];
    for (int i = tid; i < HD*C2*9; i += 256) sm.cw[i] = can_w[2*HD*C2*9 + i];
    if (tid < C2) sm.gb[tid] = gates_b[2*C2 + tid];
    if (tid < HD) sm.cb[tid] = can_b[2*HD + tid];
    gru_cell_dev(sm, tid, bi, r0, h11, false, 0.7f, h02,
                 topdown, nullptr, false, h12, nullptr, flags);
    gbar(slots, done, blk, ++ep);

    // ---- fc1 on blocks 0..99 ----
    if (blk < 100) {
        int j    = blk;
        int wave = tid >> 6;
        int lane = tid & 63;
        float acc[4] = {0.f, 0.f, 0.f, 0.f};
        const float* wr = fc1_w + (size_t)j * FEAT;
        for (int k = lane; k < FEAT; k += 64) {
            float wv = wr[k];
            #pragma unroll
            for (int q = 0; q < 4; ++q) {
                float v = h12[(size_t)(wave*4+q)*FEAT + k];
                acc[q] += fmaxf(v, 0.0f) * wv;
            }
        }
        #pragma unroll
        for (int off = 32; off > 0; off >>= 1)
            #pragma unroll
            for (int q = 0; q < 4; ++q)
                acc[q] += __shfl_down(acc[q], off);
        if (lane == 0) {
            #pragma unroll
            for (int q = 0; q < 4; ++q)
                p1[(size_t)(wave*4+q)*100 + j] = acc[q] + fc1_b[j];
        }
    }
    gbar(slots, done, blk, ++ep);

    // ---- fc2 on block 0 ----
    if (blk == 0 && tid < BB*10) {
        int b2 = tid / 10, j = tid % 10;
        float acc = fc2_b[j];
        for (int k = 0; k < 100; ++k)
            acc += fmaxf(p1[b2*100 + k], 0.0f) * fc2_w[j*100 + k];
        out[b2*10 + j] = acc;
    }
}

extern "C" void kernel_launch(void* const* d_in, const int* in_sizes, int n_in,
                              void* d_out, int out_size, void* d_ws, size_t ws_size,
                              hipStream_t stream) {
    const float* input_tensor = (const float*)d_in[0];
    const float* topdown      = (const float*)d_in[1];
    const float* icw  = (const float*)d_in[2];
    const float* icb  = (const float*)d_in[3];
    const float* gates_w = (const float*)d_in[4];
    const float* gates_b = (const float*)d_in[5];
    const float* can_w   = (const float*)d_in[6];
    const float* can_b   = (const float*)d_in[7];
    const float* td_w0 = (const float*)d_in[8];
    const float* td_b0 = (const float*)d_in[9];
    const float* td_w1 = (const float*)d_in[10];
    const float* td_b1 = (const float*)d_in[11];
    const float* fc1_w = (const float*)d_in[12];
    const float* fc1_b = (const float*)d_in[13];
    const float* fc2_w = (const float*)d_in[14];
    const float* fc2_b = (const float*)d_in[15];
    float* out = (float*)d_out;

    float* ws  = (float*)d_ws;
    float* h00 = ws;
    float* h01 = h00 + BB*HD*SP;
    float* h02 = h01 + BB*HD*SP;
    float* h10 = h02 + BB*HD*SP;
    float* h11 = h10 + BB*HD*SP;
    float* h12 = h11 + BB*HD*SP;
    float* td0 = h12 + BB*HD*SP;
    float* td1 = td0 + BB*C2*SP;
    float* p1  = td1 + BB*C2*SP;
    int*      flags = (int*)(p1 + BB*100);
    unsigned* slots = (unsigned*)(p1 + BB*100 + 16);   // 64B-aligned, 224 x 64B
    unsigned* done  = slots + NBLK*16;

    init_kernel<<<1, 256, 0, stream>>>(slots, done, flags);
    mega_kernel<<<NBLK, 256, 0, stream>>>(
        input_tensor, topdown, icw, icb, gates_w, gates_b, can_w, can_b,
        td_w0, td_b0, td_w1, td_b1, fc1_w, fc1_b, fc2_w, fc2_b, out,
        h00, h01, h02, h10, h11, h12, td0, td1, p1, flags, slots, done);
}

// Round 5
// 473.211 us; speedup vs baseline: 3.1286x; 1.0003x over previous
//
#include <hip/hip_runtime.h>
#include <cstddef>

#define HD 8
#define C2 16
#define HH 28
#define WW 28
#define BB 16
#define SP (HH*WW)           // 784
#define FEAT (HD*SP)         // 6272
#define FEAT2 (C2*SP)        // 12544

#define TILE_ROWS 2
#define NT (HH/TILE_ROWS)    // 14
#define NBLK (BB*NT)         // 224 blocks, one per (batch, row-tile)

__device__ __forceinline__ float sigf(float x) { return 1.0f / (1.0f + expf(-x)); }

struct Smem {
    float gw[C2*C2*9];                 // current node's gate weights
    float cw[HD*C2*9];                 // current node's cand weights
    float gb[C2];
    float cb[HD];
    float icw[HD*3*9];
    float icb[HD];
    float x0t[HD][TILE_ROWS+4][32];    // input-conv tile, rows r0-2..r0+3, cols -2..29
    float comb[C2][TILE_ROWS+4][32];
    union {
        float cin[C2][TILE_ROWS+2][32];
        float s_in[3][TILE_ROWS+6][36]; // raw input tile rows r0-3..r0+4, cols -3..32
    } u;
    int flags[2];
};

// Grid barrier, fully decontended: arrival = release-store into a private
// 64B line; block 0's threads poll one line each (parallel), then store the
// epoch into per-block PRIVATE release lines. Every spin loop polls a line
// no other agent touches. s_sleep(32) (~0.85us) keeps EA traffic tiny.
__device__ __forceinline__ void gbar(unsigned* arrive, unsigned* release,
                                     int blk, unsigned ep) {
    __syncthreads();
    __threadfence();   // publish this block's global writes (L2 writeback)
    if (threadIdx.x == 0)
        __hip_atomic_store(&arrive[(size_t)blk * 16], ep,
                           __ATOMIC_RELEASE, __HIP_MEMORY_SCOPE_AGENT);
    if (blk == 0) {
        int t = threadIdx.x;
        if (t < NBLK) {
            while (__hip_atomic_load(&arrive[(size_t)t * 16],
                                     __ATOMIC_RELAXED, __HIP_MEMORY_SCOPE_AGENT) < ep)
                __builtin_amdgcn_s_sleep(32);
        }
        __syncthreads();
        if (t < NBLK)
            __hip_atomic_store(&release[(size_t)t * 16], ep,
                               __ATOMIC_RELEASE, __HIP_MEMORY_SCOPE_AGENT);
    } else {
        if (threadIdx.x == 0) {
            while (__hip_atomic_load(&release[(size_t)blk * 16],
                                     __ATOMIC_RELAXED, __HIP_MEMORY_SCOPE_AGENT) < ep)
                __builtin_amdgcn_s_sleep(32);
        }
    }
    __threadfence();   // invalidate stale cached lines before reading peers' data
    __syncthreads();
}

// One ConvGRU cell for tile (bi, r0). Weights must already be in sm.gw/cw/gb/cb.
// x source: if x_lds, read sm.x0t (xscale applied); else global x (or zeros if null).
__device__ void gru_cell_dev(Smem& sm, int tid, int bi, int r0,
                             const float* x, bool x_lds, float xscale,
                             const float* h,
                             const float* td, const float* td_bias, bool use_bias,
                             float* hout, int* out_flag, int* flags) {
    // Phase A1: combined = concat([xscale*x, h]) * sigmoid(td), zero-padded tile
    for (int i = tid; i < C2*(TILE_ROWS+4)*32; i += 256) {
        int cidx = i & 31;
        int ridx = (i >> 5) % (TILE_ROWS+4);
        int c    = i / ((TILE_ROWS+4)*32);
        int row = r0 - 2 + ridx;
        int col = cidx - 2;
        float v = 0.0f;
        if (row >= 0 && row < HH && col >= 0 && col < WW) {
            float base = 0.0f;
            if (c < HD) {
                if (x_lds)      base = xscale * sm.x0t[c][ridx][cidx];
                else if (x)     base = xscale * x[((size_t)bi*HD + c)*SP + row*WW + col];
            } else {
                if (h)          base = h[((size_t)bi*HD + (c-HD))*SP + row*WW + col];
            }
            if (base != 0.0f) {
                float tdv = use_bias ? td_bias[c*SP + row*WW + col]
                                     : td[((size_t)bi*C2 + c)*SP + row*WW + col];
                v = base * sigf(tdv);
            }
        }
        sm.comb[c][ridx][cidx] = v;
    }
    // Phase A2: cand-input channels 0..7 = xscale * x (unmodulated)
    for (int i = tid; i < HD*(TILE_ROWS+2)*32; i += 256) {
        int cidx = i & 31;
        int ridx = (i >> 5) % (TILE_ROWS+2);
        int c    = i / ((TILE_ROWS+2)*32);
        int row = r0 - 1 + ridx;
        int col = cidx - 1;
        float v = 0.0f;
        if (row >= 0 && row < HH && col >= 0 && col < WW) {
            if (x_lds)      v = xscale * sm.x0t[c][ridx+1][cidx+1];
            else if (x)     v = xscale * x[((size_t)bi*HD + c)*SP + row*WW + col];
        }
        sm.u.cin[c][ridx][cidx] = v;
    }
    __syncthreads();

    // Phase B: r gates at rows r0-1..r0+2 (4) x cols -1..28 (30) x 8ch (2 halves)
    if (tid < (TILE_ROWS+2)*30*2) {
        int half  = tid & 1;
        int pos   = tid >> 1;
        int ridx2 = pos / 30;
        int cp    = pos % 30;
        float acc0 = sm.gb[half*4+0], acc1 = sm.gb[half*4+1],
              acc2 = sm.gb[half*4+2], acc3 = sm.gb[half*4+3];
        for (int ic = 0; ic < C2; ++ic) {
            float cv[3][3];
            #pragma unroll
            for (int dy = 0; dy < 3; ++dy)
                #pragma unroll
                for (int dx = 0; dx < 3; ++dx)
                    cv[dy][dx] = sm.comb[ic][ridx2+dy][cp+dx];
            const float* wp = &sm.gw[(half*4*C2 + ic)*9];
            #pragma unroll
            for (int dy = 0; dy < 3; ++dy)
                #pragma unroll
                for (int dx = 0; dx < 3; ++dx) {
                    float cvv = cv[dy][dx];
                    acc0 += cvv * wp[0*C2*9 + dy*3+dx];
                    acc1 += cvv * wp[1*C2*9 + dy*3+dx];
                    acc2 += cvv * wp[2*C2*9 + dy*3+dx];
                    acc3 += cvv * wp[3*C2*9 + dy*3+dx];
                }
        }
        int row = r0 - 1 + ridx2;
        int col = cp - 1;
        bool inb = (row >= 0 && row < HH && col >= 0 && col < WW);
        float av[4] = {acc0, acc1, acc2, acc3};
        #pragma unroll
        for (int o = 0; o < 4; ++o) {
            int ch = half*4 + o;
            float hv = 0.0f;
            if (h && inb) hv = h[((size_t)bi*HD + ch)*SP + row*WW + col];
            sm.u.cin[HD + ch][ridx2][cp] = sigf(av[o]) * hv;
        }
    }
    __syncthreads();

    // Phase C: u gate + cand conv + blend
    bool nz = false;
    for (int item = tid; item < TILE_ROWS*WW*HD; item += 256) {
        int c   = item / (TILE_ROWS*WW);
        int rem = item % (TILE_ROWS*WW);
        int rr  = rem / WW;
        int col = rem % WW;
        float uacc = sm.gb[HD + c];
        float cacc = sm.cb[c];
        for (int ic = 0; ic < C2; ++ic) {
            const float* uwp = &sm.gw[((HD + c)*C2 + ic)*9];
            const float* cwp = &sm.cw[(c*C2 + ic)*9];
            #pragma unroll
            for (int dy = 0; dy < 3; ++dy)
                #pragma unroll
                for (int dx = 0; dx < 3; ++dx) {
                    uacc += sm.comb[ic][rr+1+dy][col+1+dx] * uwp[dy*3+dx];
                    cacc += sm.u.cin[ic][rr+dy][col+dx]    * cwp[dy*3+dx];
                }
        }
        float u    = sigf(uacc);
        float cand = tanhf(cacc);
        int row = r0 + rr;
        size_t oidx = ((size_t)bi*HD + c)*SP + row*WW + col;
        float hv = h ? h[oidx] : 0.0f;
        float outv = (1.0f - u) * hv + u * cand;
        hout[oidx] = outv;
        nz |= (outv != 0.0f);
    }
    if (out_flag) {
        unsigned long long m = __ballot(nz);
        if ((tid & 63) == 0 && m) atomicOr(out_flag, 1);
    }
    __syncthreads();   // LDS safe for reuse
}

__global__ void init_kernel(unsigned* arrive, unsigned* release, int* flags) {
    int t = threadIdx.x;
    for (int i = t; i < NBLK*16; i += 256) { arrive[i] = 0u; release[i] = 0u; }
    if (t == 0) { flags[0] = 0; flags[1] = 0; }
}

__global__ __launch_bounds__(256)
void mega_kernel(const float* __restrict__ input_tensor, const float* __restrict__ topdown,
                 const float* __restrict__ icw, const float* __restrict__ icb,
                 const float* __restrict__ gates_w, const float* __restrict__ gates_b,
                 const float* __restrict__ can_w, const float* __restrict__ can_b,
                 const float* __restrict__ td_w0, const float* __restrict__ td_b0,
                 const float* __restrict__ td_w1, const float* __restrict__ td_b1,
                 const float* __restrict__ fc1_w, const float* __restrict__ fc1_b,
                 const float* __restrict__ fc2_w, const float* __restrict__ fc2_b,
                 float* __restrict__ out,
                 float* __restrict__ h00, float* __restrict__ h01, float* __restrict__ h02,
                 float* __restrict__ h10, float* __restrict__ h11, float* __restrict__ h12,
                 float* __restrict__ td0, float* __restrict__ td1,
                 float* __restrict__ p1,
                 int* flags, unsigned* arrive, unsigned* release)
{
    const int tid = threadIdx.x;
    const int blk = blockIdx.x;
    const int bi  = blk / NT;
    const int r0  = (blk % NT) * TILE_ROWS;

    __shared__ Smem sm;
    unsigned ep = 0;

    // ---- Phase S0 (no prior barrier): node-0 weights + local input-conv tile ----
    for (int i = tid; i < C2*C2*9; i += 256) sm.gw[i] = gates_w[i];
    for (int i = tid; i < HD*C2*9; i += 256) sm.cw[i] = can_w[i];
    if (tid < C2) sm.gb[tid] = gates_b[tid];
    if (tid < HD) sm.cb[tid] = can_b[tid];
    for (int i = tid; i < HD*3*9; i += 256) sm.icw[i] = icw[i];
    if (tid < HD) sm.icb[tid] = icb[tid];

    // raw input tile rows r0-3..r0+4, cols -3..32 (zero-padded)
    for (int i = tid; i < 3*(TILE_ROWS+6)*36; i += 256) {
        int ci = i % 36;
        int ri = (i / 36) % (TILE_ROWS+6);
        int c  = i / ((TILE_ROWS+6)*36);
        int row = r0 - 3 + ri;
        int col = ci - 3;
        float v = 0.0f;
        if (row >= 0 && row < HH && col >= 0 && col < WW)
            v = input_tensor[((size_t)bi*3 + c)*SP + row*WW + col];
        sm.u.s_in[c][ri][ci] = v;
    }
    __syncthreads();

    // x0 tile with halo: rows r0-2..r0+3, cols -2..29
    for (int i = tid; i < HD*(TILE_ROWS+4)*32; i += 256) {
        int ci = i & 31;
        int ri = (i >> 5) % (TILE_ROWS+4);
        int oc = i / ((TILE_ROWS+4)*32);
        int row = r0 - 2 + ri;
        int col = ci - 2;
        float v = 0.0f;
        if (row >= 0 && row < HH && col >= 0 && col < WW) {
            float acc = sm.icb[oc];
            for (int ic = 0; ic < 3; ++ic)
                #pragma unroll
                for (int dy = 0; dy < 3; ++dy)
                    #pragma unroll
                    for (int dx = 0; dx < 3; ++dx)
                        acc += sm.u.s_in[ic][ri+dy][ci+dx]
                             * sm.icw[((oc*3 + ic)*3 + dy)*3 + dx];
            v = acc;
        }
        sm.x0t[oc][ri][ci] = v;
    }
    __syncthreads();

    // Sweep-0 node 0: x = x0 tile, h = 0, td = bias-reshape
    gru_cell_dev(sm, tid, bi, r0, nullptr, true, 1.0f, nullptr,
                 nullptr, td_b0, true, h00, nullptr, flags);

    // Sweep-0 nodes 1,2: x=0, h=0 => comb==0 regardless of td, so the cell
    // reduces exactly to per-channel constants sig(gb_u[c]) * tanh(cb[c]).
    {
        bool nz1 = false, nz2 = false;
        for (int item = tid; item < TILE_ROWS*WW*HD; item += 256) {
            int c   = item / (TILE_ROWS*WW);
            int rem = item % (TILE_ROWS*WW);
            int rr  = rem / WW;
            int col = rem % WW;
            float v1 = sigf(gates_b[C2 + HD + c])   * tanhf(can_b[HD + c]);
            float v2 = sigf(gates_b[2*C2 + HD + c]) * tanhf(can_b[2*HD + c]);
            size_t oidx = ((size_t)bi*HD + c)*SP + (r0 + rr)*WW + col;
            h01[oidx] = v1;
            h02[oidx] = v2;
            nz1 |= (v1 != 0.0f);
            nz2 |= (v2 != 0.0f);
        }
        unsigned long long m1 = __ballot(nz1), m2 = __ballot(nz2);
        if ((tid & 63) == 0) {
            if (m1) atomicOr(&flags[0], 1);
            if (m2) atomicOr(&flags[1], 1);
        }
    }
    gbar(arrive, release, blk, ++ep);

    // flags are now globally consistent -> uniform branch across the grid
    if (tid == 0) {
        sm.flags[0] = __hip_atomic_load(&flags[0], __ATOMIC_RELAXED, __HIP_MEMORY_SCOPE_AGENT);
        sm.flags[1] = __hip_atomic_load(&flags[1], __ATOMIC_RELAXED, __HIP_MEMORY_SCOPE_AGENT);
    }
    __syncthreads();
    const int f0 = sm.flags[0], f1 = sm.flags[1];

    // ---- td projections (dead on this data; kept for generality) ----
    if (f0 | f1) {
        int gtid = blk*256 + tid;
        if (gtid < 2*FEAT2) {
            int nn = gtid / FEAT2;
            int j  = gtid % FEAT2;
            if (nn ? f1 : f0) {
                const float* hin  = nn ? h02 : h01;
                const float* w    = nn ? td_w1 : td_w0;
                const float* bias = nn ? td_b1 : td_b0;
                float* o          = nn ? td1 : td0;
                float scale       = nn ? 0.5f : 0.6f;
                float acc[BB];
                #pragma unroll
                for (int q = 0; q < BB; ++q) acc[q] = 0.0f;
                const float* wr = w + (size_t)j * FEAT;
                for (int k = 0; k < FEAT; ++k) {
                    float wv = wr[k];
                    #pragma unroll
                    for (int q = 0; q < BB; ++q)
                        acc[q] += (scale * hin[(size_t)q*FEAT + k]) * wv;
                }
                #pragma unroll
                for (int q = 0; q < BB; ++q) o[(size_t)q*FEAT2 + j] = acc[q] + bias[j];
            }
        }
        gbar(arrive, release, blk, ++ep);
    }

    // ---- Sweep 1, node 0 (node-0 weights still resident in LDS) ----
    gru_cell_dev(sm, tid, bi, r0, nullptr, true, 1.0f, h00,
                 td0, td_b0, f0 == 0, h10, nullptr, flags);
    gbar(arrive, release, blk, ++ep);

    // ---- Sweep 1, node 1 ----
    for (int i = tid; i < C2*C2*9; i += 256) sm.gw[i] = gates_w[C2*C2*9 + i];
    for (int i = tid; i < HD*C2*9; i += 256) sm.cw[i] = can_w[HD*C2*9 + i];
    if (tid < C2) sm.gb[tid] = gates_b[C2 + tid];
    if (tid < HD) sm.cb[tid] = can_b[HD + tid];
    __syncthreads();
    gru_cell_dev(sm, tid, bi, r0, h10, false, 0.8f, h01,
                 td1, td_b1, f1 == 0, h11, nullptr, flags);
    gbar(arrive, release, blk, ++ep);

    // ---- Sweep 1, node 2 ----
    for (int i = tid; i < C2*C2*9; i += 256) sm.gw[i] = gates_w[2*C2*C2*9 + i];
    for (int i = tid; i < HD*C2*9; i += 256) sm.cw[i] = can_w[2*HD*C2*9 + i];
    if (tid < C2) sm.gb[tid] = gates_b[2*C2 + tid];
    if (tid < HD) sm.cb[tid] = can_b[2*HD + tid];
    __syncthreads();
    gru_cell_dev(sm, tid, bi, r0, h11, false, 0.7f, h02,
                 topdown, nullptr, false, h12, nullptr, flags);
    gbar(arrive, release, blk, ++ep);

    // ---- fc1 on blocks 0..99 ----
    if (blk < 100) {
        int j    = blk;
        int wave = tid >> 6;
        int lane = tid & 63;
        float acc[4] = {0.f, 0.f, 0.f, 0.f};
        const float* wr = fc1_w + (size_t)j * FEAT;
        for (int k = lane; k < FEAT; k += 64) {
            float wv = wr[k];
            #pragma unroll
            for (int q = 0; q < 4; ++q) {
                float v = h12[(size_t)(wave*4+q)*FEAT + k];
                acc[q] += fmaxf(v, 0.0f) * wv;
            }
        }
        #pragma unroll
        for (int off = 32; off > 0; off >>= 1)
            #pragma unroll
            for (int q = 0; q < 4; ++q)
                acc[q] += __shfl_down(acc[q], off);
        if (lane == 0) {
            #pragma unroll
            for (int q = 0; q < 4; ++q)
                p1[(size_t)(wave*4+q)*100 + j] = acc[q] + fc1_b[j];
        }
    }
    gbar(arrive, release, blk, ++ep);

    // ---- fc2 on block 0 ----
    if (blk == 0 && tid < BB*10) {
        int b2 = tid / 10, j = tid % 10;
        float acc = fc2_b[j];
        for (int k = 0; k < 100; ++k)
            acc += fmaxf(p1[b2*100 + k], 0.0f) * fc2_w[j*100 + k];
        out[b2*10 + j] = acc;
    }
}

extern "C" void kernel_launch(void* const* d_in, const int* in_sizes, int n_in,
                              void* d_out, int out_size, void* d_ws, size_t ws_size,
                              hipStream_t stream) {
    const float* input_tensor = (const float*)d_in[0];
    const float* topdown      = (const float*)d_in[1];
    const float* icw  = (const float*)d_in[2];
    const float* icb  = (const float*)d_in[3];
    const float* gates_w = (const float*)d_in[4];
    const float* gates_b = (const float*)d_in[5];
    const float* can_w   = (const float*)d_in[6];
    const float* can_b   = (const float*)d_in[7];
    const float* td_w0 = (const float*)d_in[8];
    const float* td_b0 = (const float*)d_in[9];
    const float* td_w1 = (const float*)d_in[10];
    const float* td_b1 = (const float*)d_in[11];
    const float* fc1_w = (const float*)d_in[12];
    const float* fc1_b = (const float*)d_in[13];
    const float* fc2_w = (const float*)d_in[14];
    const float* fc2_b = (const float*)d_in[15];
    float* out = (float*)d_out;

    float* ws  = (float*)d_ws;
    float* h00 = ws;
    float* h01 = h00 + BB*HD*SP;
    float* h02 = h01 + BB*HD*SP;
    float* h10 = h02 + BB*HD*SP;
    float* h11 = h10 + BB*HD*SP;
    float* h12 = h11 + BB*HD*SP;
    float* td0 = h12 + BB*HD*SP;
    float* td1 = td0 + BB*C2*SP;
    float* p1  = td1 + BB*C2*SP;

    // Barrier state isolated on its own pages, far from live data.
    char* bar_base = (char*)d_ws + (8u << 20);           // ws + 8 MiB
    unsigned* arrive  = (unsigned*)bar_base;             // 224 x 64B
    unsigned* release = arrive + NBLK*16;                // 224 x 64B
    int*      flags   = (int*)(release + NBLK*16);

    init_kernel<<<1, 256, 0, stream>>>(arrive, release, flags);
    mega_kernel<<<NBLK, 256, 0, stream>>>(
        input_tensor, topdown, icw, icb, gates_w, gates_b, can_w, can_b,
        td_w0, td_b0, td_w1, td_b1, fc1_w, fc1_b, fc2_w, fc2_b, out,
        h00, h01, h02, h10, h11, h12, td0, td1, p1, flags, arrive, release);
}